// Round 11
// baseline (47.827 us; speedup 1.0000x reference)
//
#include <hip/hip_runtime.h>
#include <math.h>
#include <stdint.h>

#define DEG 16
#define FDIM 128
#define EPSV 1e-12f

typedef int   iv4 __attribute__((ext_vector_type(4)));
typedef float fv4 __attribute__((ext_vector_type(4)));

#if __has_builtin(__builtin_amdgcn_sdot4)
#define SDOT4(a, b, c) __builtin_amdgcn_sdot4((int)(a), (int)(b), (c), false)
#else
__device__ __forceinline__ int SDOT4(uint32_t a, uint32_t b, int c) {
    return c + (int)(int8_t)(a & 255u) * (int)(int8_t)(b & 255u)
             + (int)(int8_t)((a >> 8) & 255u) * (int)(int8_t)((b >> 8) & 255u)
             + (int)(int8_t)((a >> 16) & 255u) * (int)(int8_t)((b >> 16) & 255u)
             + (int)(int8_t)(a >> 24) * (int)(int8_t)(b >> 24);
}
#endif

// Prep: one wave per row. rn = rsqrt(|x|^2+eps), rowmax, SIGNED-i8 quant row.
// x is read-once -> nontemporal loads (don't evict xq being written).
__global__ void agnn_prep_i8(const float* __restrict__ x,
                             uint32_t* __restrict__ xq,
                             float2* __restrict__ prm, int n) {
    int row  = (blockIdx.x * blockDim.x + threadIdx.x) >> 6;
    int lane = threadIdx.x & 63;
    if (row >= n) return;
    const float vx = __builtin_nontemporal_load(x + (size_t)row * FDIM + lane * 2);
    const float vy = __builtin_nontemporal_load(x + (size_t)row * FDIM + lane * 2 + 1);
    float s2 = vx * vx + vy * vy;
    float am = fmaxf(fabsf(vx), fabsf(vy));
#pragma unroll
    for (int off = 32; off >= 1; off >>= 1) {
        s2 += __shfl_xor(s2, off);
        am = fmaxf(am, __shfl_xor(am, off));
    }
    const float rn  = rsqrtf(s2 + EPSV);
    const float amc = fmaxf(am, 1e-20f);
    const float is  = 127.f / amc;
    const float s   = amc * (1.f / 127.f);
    const int q0 = (int)rintf(vx * is);        // in [-127,127]
    const int q1 = (int)rintf(vy * is);
    reinterpret_cast<uint16_t*>(xq)[(size_t)row * 64 + lane] =
        (uint16_t)((q0 & 0xff) | ((q1 & 0xff) << 8));
    if (lane == 0) prm[row] = make_float2(s, s * rn);
}

// Main v10 = v8 body (best so far) + persistent grid-stride at FULL
// occupancy (8 waves/SIMD, no pipeline regs) + streaming-memory hygiene:
//  - out written with nontemporal (no-allocate) stores: 25.6MB no longer
//    evicts xq from the 4MiB per-XCD L2 -> fewer gather fills
//  - col_id read nontemporal (read-once stream)
//  - store split across groups 0/1 (fewer serialized store slots)
__global__ __launch_bounds__(256, 8)
void agnn_main_v10(const uint32_t* __restrict__ xq,
                   const int* __restrict__ col_id,
                   const float2* __restrict__ prm,
                   const float* __restrict__ beta,
                   float* __restrict__ out, int n) {
    const int lane = threadIdx.x & 63;
    const int wid  = (int)((blockIdx.x * blockDim.x + threadIdx.x) >> 6);
    const int nw   = (int)((gridDim.x * blockDim.x) >> 6);
    const int g = lane >> 4;
    const int t = lane & 15;
    const float b = beta[0];

    for (int i = wid; i < n; i += nw) {
        // row gathers first (L2-miss path), params after (L2-hot)
        const iv4 c4 = __builtin_nontemporal_load(
            reinterpret_cast<const iv4*>(col_id + (size_t)i * DEG + 4 * g));
        const uint2 xi = *reinterpret_cast<const uint2*>(xq + (size_t)i * 32 + t * 2);
        const uint2 r0 = *reinterpret_cast<const uint2*>(xq + (size_t)c4.x * 32 + t * 2);
        const uint2 r1 = *reinterpret_cast<const uint2*>(xq + (size_t)c4.y * 32 + t * 2);
        const uint2 r2 = *reinterpret_cast<const uint2*>(xq + (size_t)c4.z * 32 + t * 2);
        const uint2 r3 = *reinterpret_cast<const uint2*>(xq + (size_t)c4.w * 32 + t * 2);
        const float2 pi = prm[i];
        const float2 p0 = prm[c4.x];
        const float2 p1 = prm[c4.y];
        const float2 p2 = prm[c4.z];
        const float2 p3 = prm[c4.w];

        // exact integer partial dots (8 dims per lane)
        int d0 = SDOT4(r0.x, xi.x, SDOT4(r0.y, xi.y, 0));
        int d1 = SDOT4(r1.x, xi.x, SDOT4(r1.y, xi.y, 0));
        int d2 = SDOT4(r2.x, xi.x, SDOT4(r2.y, xi.y, 0));
        int d3 = SDOT4(r3.x, xi.x, SDOT4(r3.y, xi.y, 0));

        // intra-group (16-lane) butterfly, exact int adds
#pragma unroll
        for (int off = 1; off < 16; off <<= 1) {
            d0 += __shfl_xor(d0, off);
            d1 += __shfl_xor(d1, off);
            d2 += __shfl_xor(d2, off);
            d3 += __shfl_xor(d3, off);
        }

        // e_r = beta * (s_i rn_i) * (s_j rn_j) * D_r
        const float bt = b * pi.y;
        float w0 = __expf(bt * p0.y * (float)d0);
        float w1 = __expf(bt * p1.y * (float)d1);
        float w2 = __expf(bt * p2.y * (float)d2);
        float w3 = __expf(bt * p3.y * (float)d3);

        float sum = (w0 + w1) + (w2 + w3);
        sum += __shfl_xor(sum, 16);
        sum += __shfl_xor(sum, 32);
        const float inv = 1.f / sum;
        w0 *= inv * p0.x;                      // alpha_r * s_r
        w1 *= inv * p1.x;
        w2 *= inv * p2.x;
        w3 *= inv * p3.x;

        // aggregation: acc[d] = sum_r w_r * i8_r[d]
        float acc[8];
#pragma unroll
        for (int k = 0; k < 4; ++k) {
            const float f0 = (float)(int)(int8_t)((r0.x >> (8 * k)) & 255u);
            const float f1 = (float)(int)(int8_t)((r1.x >> (8 * k)) & 255u);
            const float f2 = (float)(int)(int8_t)((r2.x >> (8 * k)) & 255u);
            const float f3 = (float)(int)(int8_t)((r3.x >> (8 * k)) & 255u);
            acc[k] = fmaf(w3, f3, fmaf(w2, f2, fmaf(w1, f1, w0 * f0)));
        }
#pragma unroll
        for (int k = 0; k < 4; ++k) {
            const float f0 = (float)(int)(int8_t)((r0.y >> (8 * k)) & 255u);
            const float f1 = (float)(int)(int8_t)((r1.y >> (8 * k)) & 255u);
            const float f2 = (float)(int)(int8_t)((r2.y >> (8 * k)) & 255u);
            const float f3 = (float)(int)(int8_t)((r3.y >> (8 * k)) & 255u);
            acc[4 + k] = fmaf(w3, f3, fmaf(w2, f2, fmaf(w1, f1, w0 * f0)));
        }

        // cross-group reduce
#pragma unroll
        for (int k = 0; k < 8; ++k) acc[k] += __shfl_xor(acc[k], 16);
#pragma unroll
        for (int k = 0; k < 8; ++k) acc[k] += __shfl_xor(acc[k], 32);

        // streaming store (no L2 allocate), split across groups 0/1
        if (g == 0) {
            fv4 v; v.x = acc[0]; v.y = acc[1]; v.z = acc[2]; v.w = acc[3];
            __builtin_nontemporal_store(
                v, reinterpret_cast<fv4*>(out + (size_t)i * FDIM + t * 8));
        } else if (g == 1) {
            fv4 v; v.x = acc[4]; v.y = acc[5]; v.z = acc[6]; v.w = acc[7];
            __builtin_nontemporal_store(
                v, reinterpret_cast<fv4*>(out + (size_t)i * FDIM + t * 8 + 4));
        }
    }
}

// ---------- fp32 fallback (only if ws is somehow too small) ----------
__global__ void agnn_rnorm_kernel(const float* __restrict__ x,
                                  float* __restrict__ rn, int n) {
    int wave = (blockIdx.x * blockDim.x + threadIdx.x) >> 6;
    int lane = threadIdx.x & 63;
    if (wave >= n) return;
    const float2 v = *reinterpret_cast<const float2*>(x + (size_t)wave * FDIM + lane * 2);
    float s = v.x * v.x + v.y * v.y;
#pragma unroll
    for (int off = 32; off >= 1; off >>= 1)
        s += __shfl_xor(s, off);
    if (lane == 0) rn[wave] = rsqrtf(s + EPSV);
}

__global__ void agnn_main_f32(const float* __restrict__ x,
                              const int* __restrict__ col_id,
                              const float* __restrict__ rn,
                              const float* __restrict__ beta,
                              float* __restrict__ out, int n) {
    int wave = (blockIdx.x * blockDim.x + threadIdx.x) >> 6;
    int lane = threadIdx.x & 63;
    if (wave >= n) return;
    const int node = wave;
    const float b   = beta[0];
    const float rni = rn[node];
    const float2 xi = *reinterpret_cast<const float2*>(x + (size_t)node * FDIM + lane * 2);
    int cidx = col_id[node * DEG + (lane & 15)];
    float2 xj[DEG];
    float  p[DEG];
    float  rnj[DEG];
#pragma unroll
    for (int k = 0; k < DEG; ++k) {
        int cj = __shfl(cidx, k);
        const float2 v = *reinterpret_cast<const float2*>(x + (size_t)cj * FDIM + lane * 2);
        xj[k] = v; rnj[k] = rn[cj];
        p[k] = fmaf(xi.x, v.x, xi.y * v.y);
    }
#pragma unroll
    for (int off = 32; off >= 1; off >>= 1) {
#pragma unroll
        for (int k = 0; k < DEG; ++k)
            p[k] += __shfl_xor(p[k], off);
    }
    const float brni = b * rni;
#pragma unroll
    for (int k = 0; k < DEG; ++k) p[k] *= brni * rnj[k];
    float m = p[0];
#pragma unroll
    for (int k = 1; k < DEG; ++k) m = fmaxf(m, p[k]);
    float s = 0.f;
#pragma unroll
    for (int k = 0; k < DEG; ++k) { p[k] = __expf(p[k] - m); s += p[k]; }
    const float inv = 1.0f / s;
    float2 acc = make_float2(0.f, 0.f);
#pragma unroll
    for (int k = 0; k < DEG; ++k) {
        const float a = p[k] * inv;
        acc.x = fmaf(a, xj[k].x, acc.x);
        acc.y = fmaf(a, xj[k].y, acc.y);
    }
    *reinterpret_cast<float2*>(out + (size_t)node * FDIM + lane * 2) = acc;
}

extern "C" void kernel_launch(void* const* d_in, const int* in_sizes, int n_in,
                              void* d_out, int out_size, void* d_ws, size_t ws_size,
                              hipStream_t stream) {
    const float* x      = (const float*)d_in[0];
    const int*   col_id = (const int*)d_in[3];
    const float* beta   = (const float*)d_in[4];
    float*       out    = (float*)d_out;

    const int n = in_sizes[0] / FDIM;            // 50000

    const int block = 256;                       // 4 waves / block
    const int wavesPerBlock = block / 64;
    const int gridPrep = (n + wavesPerBlock - 1) / wavesPerBlock;

    const size_t xq_bytes = (size_t)n * FDIM;               // 6.4 MB i8 rows
    const size_t need = xq_bytes + (size_t)n * sizeof(float2);

    if (ws_size >= need) {
        uint32_t* xq  = (uint32_t*)d_ws;
        float2*   prm = (float2*)((char*)d_ws + xq_bytes);
        agnn_prep_i8<<<gridPrep, block, 0, stream>>>(x, xq, prm, n);
        // persistent full-occupancy main: 2048 blocks = 8192 waves
        // (8 waves/SIMD), each wave grid-strides over ~6 nodes
        agnn_main_v10<<<2048, block, 0, stream>>>(xq, col_id, prm, beta, out, n);
    } else {
        float* rn = (float*)d_ws;
        agnn_rnorm_kernel<<<gridPrep, block, 0, stream>>>(x, rn, n);
        agnn_main_f32<<<gridPrep, block, 0, stream>>>(x, col_id, rn, beta, out, n);
    }
}

// Round 12
// 37.152 us; speedup vs baseline: 1.2873x; 1.2873x over previous
//
#include <hip/hip_runtime.h>
#include <math.h>
#include <stdint.h>

#define DEG 16
#define FDIM 128
#define EPSV 1e-12f

#if __has_builtin(__builtin_amdgcn_sdot4)
#define SDOT4(a, b, c) __builtin_amdgcn_sdot4((int)(a), (int)(b), (c), false)
#else
__device__ __forceinline__ int SDOT4(uint32_t a, uint32_t b, int c) {
    return c + (int)(int8_t)(a & 255u) * (int)(int8_t)(b & 255u)
             + (int)(int8_t)((a >> 8) & 255u) * (int)(int8_t)((b >> 8) & 255u)
             + (int)(int8_t)((a >> 16) & 255u) * (int)(int8_t)((b >> 16) & 255u)
             + (int)(int8_t)(a >> 24) * (int)(int8_t)(b >> 24);
}
#endif

// Prep: one wave per row. rn = rsqrt(|x|^2+eps), rowmax, SIGNED-i8 quant row.
// prm[row] = (s, s*rn)  [float2, 400KB -> L2-resident]
__global__ void agnn_prep_i8(const float* __restrict__ x,
                             uint32_t* __restrict__ xq,
                             float2* __restrict__ prm, int n) {
    int row  = (blockIdx.x * blockDim.x + threadIdx.x) >> 6;
    int lane = threadIdx.x & 63;
    if (row >= n) return;
    const float2 v = *reinterpret_cast<const float2*>(x + (size_t)row * FDIM + lane * 2);
    float s2 = v.x * v.x + v.y * v.y;
    float am = fmaxf(fabsf(v.x), fabsf(v.y));
#pragma unroll
    for (int off = 32; off >= 1; off >>= 1) {
        s2 += __shfl_xor(s2, off);
        am = fmaxf(am, __shfl_xor(am, off));
    }
    const float rn  = rsqrtf(s2 + EPSV);
    const float amc = fmaxf(am, 1e-20f);
    const float is  = 127.f / amc;
    const float s   = amc * (1.f / 127.f);
    const int q0 = (int)rintf(v.x * is);       // in [-127,127]
    const int q1 = (int)rintf(v.y * is);
    reinterpret_cast<uint16_t*>(xq)[(size_t)row * 64 + lane] =
        (uint16_t)((q0 & 0xff) | ((q1 & 0xff) << 8));
    if (lane == 0) prm[row] = make_float2(s, s * rn);
}

// Main v8 (best verified: 36.8us total): one wave per node, 4 groups x 16
// lanes; group g owns neighbors 4g..4g+3, lane t owns dims [8t,8t+8).
// Signed i8, exact integer dots via v_dot4_i32_i8, float2 params.
__global__ __launch_bounds__(256, 8)
void agnn_main_v8(const uint32_t* __restrict__ xq,
                  const int* __restrict__ col_id,
                  const float2* __restrict__ prm,
                  const float* __restrict__ beta,
                  float* __restrict__ out, int n) {
    int node = (blockIdx.x * blockDim.x + threadIdx.x) >> 6;
    int lane = threadIdx.x & 63;
    if (node >= n) return;
    const int g = lane >> 4;
    const int t = lane & 15;

    // row gathers first (L2-miss path), params after (L2-hot)
    const int4  c4 = *reinterpret_cast<const int4*>(col_id + node * DEG + 4 * g);
    const uint2 xi = *reinterpret_cast<const uint2*>(xq + (size_t)node * 32 + t * 2);
    const uint2 r0 = *reinterpret_cast<const uint2*>(xq + (size_t)c4.x * 32 + t * 2);
    const uint2 r1 = *reinterpret_cast<const uint2*>(xq + (size_t)c4.y * 32 + t * 2);
    const uint2 r2 = *reinterpret_cast<const uint2*>(xq + (size_t)c4.z * 32 + t * 2);
    const uint2 r3 = *reinterpret_cast<const uint2*>(xq + (size_t)c4.w * 32 + t * 2);
    const float2 pi = prm[node];
    const float2 p0 = prm[c4.x];
    const float2 p1 = prm[c4.y];
    const float2 p2 = prm[c4.z];
    const float2 p3 = prm[c4.w];
    const float b = beta[0];

    // exact integer partial dots (8 dims per lane)
    int d0 = SDOT4(r0.x, xi.x, SDOT4(r0.y, xi.y, 0));
    int d1 = SDOT4(r1.x, xi.x, SDOT4(r1.y, xi.y, 0));
    int d2 = SDOT4(r2.x, xi.x, SDOT4(r2.y, xi.y, 0));
    int d3 = SDOT4(r3.x, xi.x, SDOT4(r3.y, xi.y, 0));

    // intra-group (16-lane) butterfly, exact int adds
#pragma unroll
    for (int off = 1; off < 16; off <<= 1) {
        d0 += __shfl_xor(d0, off);
        d1 += __shfl_xor(d1, off);
        d2 += __shfl_xor(d2, off);
        d3 += __shfl_xor(d3, off);
    }

    // e_r = beta * (s_i rn_i) * (s_j rn_j) * D_r
    const float bt = b * pi.y;
    float w0 = __expf(bt * p0.y * (float)d0);
    float w1 = __expf(bt * p1.y * (float)d1);
    float w2 = __expf(bt * p2.y * (float)d2);
    float w3 = __expf(bt * p3.y * (float)d3);

    float sum = (w0 + w1) + (w2 + w3);
    sum += __shfl_xor(sum, 16);
    sum += __shfl_xor(sum, 32);
    const float inv = 1.f / sum;
    w0 *= inv * p0.x;                          // alpha_r * s_r
    w1 *= inv * p1.x;
    w2 *= inv * p2.x;
    w3 *= inv * p3.x;

    // aggregation: acc[d] = sum_r w_r * i8_r[d]
    float acc[8];
#pragma unroll
    for (int k = 0; k < 4; ++k) {
        const float f0 = (float)(int)(int8_t)((r0.x >> (8 * k)) & 255u);
        const float f1 = (float)(int)(int8_t)((r1.x >> (8 * k)) & 255u);
        const float f2 = (float)(int)(int8_t)((r2.x >> (8 * k)) & 255u);
        const float f3 = (float)(int)(int8_t)((r3.x >> (8 * k)) & 255u);
        acc[k] = fmaf(w3, f3, fmaf(w2, f2, fmaf(w1, f1, w0 * f0)));
    }
#pragma unroll
    for (int k = 0; k < 4; ++k) {
        const float f0 = (float)(int)(int8_t)((r0.y >> (8 * k)) & 255u);
        const float f1 = (float)(int)(int8_t)((r1.y >> (8 * k)) & 255u);
        const float f2 = (float)(int)(int8_t)((r2.y >> (8 * k)) & 255u);
        const float f3 = (float)(int)(int8_t)((r3.y >> (8 * k)) & 255u);
        acc[4 + k] = fmaf(w3, f3, fmaf(w2, f2, fmaf(w1, f1, w0 * f0)));
    }

    // cross-group reduce
#pragma unroll
    for (int k = 0; k < 8; ++k) acc[k] += __shfl_xor(acc[k], 16);
#pragma unroll
    for (int k = 0; k < 8; ++k) acc[k] += __shfl_xor(acc[k], 32);

    if (g == 0) {
        float4* op = reinterpret_cast<float4*>(out + (size_t)node * FDIM + t * 8);
        op[0] = make_float4(acc[0], acc[1], acc[2], acc[3]);
        op[1] = make_float4(acc[4], acc[5], acc[6], acc[7]);
    }
}

// ---------- fp32 fallback (only if ws is somehow too small) ----------
__global__ void agnn_rnorm_kernel(const float* __restrict__ x,
                                  float* __restrict__ rn, int n) {
    int wave = (blockIdx.x * blockDim.x + threadIdx.x) >> 6;
    int lane = threadIdx.x & 63;
    if (wave >= n) return;
    const float2 v = *reinterpret_cast<const float2*>(x + (size_t)wave * FDIM + lane * 2);
    float s = v.x * v.x + v.y * v.y;
#pragma unroll
    for (int off = 32; off >= 1; off >>= 1)
        s += __shfl_xor(s, off);
    if (lane == 0) rn[wave] = rsqrtf(s + EPSV);
}

__global__ void agnn_main_f32(const float* __restrict__ x,
                              const int* __restrict__ col_id,
                              const float* __restrict__ rn,
                              const float* __restrict__ beta,
                              float* __restrict__ out, int n) {
    int wave = (blockIdx.x * blockDim.x + threadIdx.x) >> 6;
    int lane = threadIdx.x & 63;
    if (wave >= n) return;
    const int node = wave;
    const float b   = beta[0];
    const float rni = rn[node];
    const float2 xi = *reinterpret_cast<const float2*>(x + (size_t)node * FDIM + lane * 2);
    int cidx = col_id[node * DEG + (lane & 15)];
    float2 xj[DEG];
    float  p[DEG];
    float  rnj[DEG];
#pragma unroll
    for (int k = 0; k < DEG; ++k) {
        int cj = __shfl(cidx, k);
        const float2 v = *reinterpret_cast<const float2*>(x + (size_t)cj * FDIM + lane * 2);
        xj[k] = v; rnj[k] = rn[cj];
        p[k] = fmaf(xi.x, v.x, xi.y * v.y);
    }
#pragma unroll
    for (int off = 32; off >= 1; off >>= 1) {
#pragma unroll
        for (int k = 0; k < DEG; ++k)
            p[k] += __shfl_xor(p[k], off);
    }
    const float brni = b * rni;
#pragma unroll
    for (int k = 0; k < DEG; ++k) p[k] *= brni * rnj[k];
    float m = p[0];
#pragma unroll
    for (int k = 1; k < DEG; ++k) m = fmaxf(m, p[k]);
    float s = 0.f;
#pragma unroll
    for (int k = 0; k < DEG; ++k) { p[k] = __expf(p[k] - m); s += p[k]; }
    const float inv = 1.0f / s;
    float2 acc = make_float2(0.f, 0.f);
#pragma unroll
    for (int k = 0; k < DEG; ++k) {
        const float a = p[k] * inv;
        acc.x = fmaf(a, xj[k].x, acc.x);
        acc.y = fmaf(a, xj[k].y, acc.y);
    }
    *reinterpret_cast<float2*>(out + (size_t)node * FDIM + lane * 2) = acc;
}

extern "C" void kernel_launch(void* const* d_in, const int* in_sizes, int n_in,
                              void* d_out, int out_size, void* d_ws, size_t ws_size,
                              hipStream_t stream) {
    const float* x      = (const float*)d_in[0];
    const int*   col_id = (const int*)d_in[3];
    const float* beta   = (const float*)d_in[4];
    float*       out    = (float*)d_out;

    const int n = in_sizes[0] / FDIM;            // 50000

    const int block = 256;                       // 4 waves / block
    const int wavesPerBlock = block / 64;
    const int grid = (n + wavesPerBlock - 1) / wavesPerBlock;

    const size_t xq_bytes = (size_t)n * FDIM;               // 6.4 MB i8 rows
    const size_t need = xq_bytes + (size_t)n * sizeof(float2);

    if (ws_size >= need) {
        uint32_t* xq  = (uint32_t*)d_ws;
        float2*   prm = (float2*)((char*)d_ws + xq_bytes);
        agnn_prep_i8<<<grid, block, 0, stream>>>(x, xq, prm, n);
        agnn_main_v8<<<grid, block, 0, stream>>>(xq, col_id, prm, beta, out, n);
    } else {
        float* rn = (float*)d_ws;
        agnn_rnorm_kernel<<<grid, block, 0, stream>>>(x, rn, n);
        agnn_main_f32<<<grid, block, 0, stream>>>(x, col_id, rn, beta, out, n);
    }
}